// Round 1
// baseline (1410.511 us; speedup 1.0000x reference)
//
#include <hip/hip_runtime.h>

// ---------------------------------------------------------------------------
// GNN forward: GCNConv(64->64, sym-norm, self-loops) + ReLU + residual,
// then MLP 64->256->256->1 with ReLU.
// Strategy: build CSR (dst-indexed) on device, pull-based aggregation
// (no fp32 atomics), dinv folded into h, fused MLP (h1/h2 never hit HBM).
// ---------------------------------------------------------------------------

__global__ void k_count(const int* __restrict__ dst, int E, int* __restrict__ counts) {
    int i = blockIdx.x * 256 + threadIdx.x;
    if (i < E) atomicAdd(&counts[dst[i]], 1);
}

__global__ __launch_bounds__(1024) void k_scan1(const int* __restrict__ counts, int N,
                                                int* __restrict__ offsets, int* __restrict__ bsum) {
    __shared__ int s[1024];
    int t = threadIdx.x;
    int i = blockIdx.x * 1024 + t;
    int v = (i < N) ? counts[i] : 0;
    s[t] = v;
    __syncthreads();
    for (int off = 1; off < 1024; off <<= 1) {
        int a = (t >= off) ? s[t - off] : 0;
        __syncthreads();
        s[t] += a;
        __syncthreads();
    }
    if (i < N) offsets[i] = s[t] - v;     // exclusive within block
    if (t == 1023) bsum[blockIdx.x] = s[t];
}

__global__ void k_scantop(int* bsum, int nb) {
    if (threadIdx.x == 0 && blockIdx.x == 0) {
        int acc = 0;
        for (int b = 0; b < nb; b++) { int v = bsum[b]; bsum[b] = acc; acc += v; }
    }
}

__global__ void k_scanadd(int* __restrict__ offsets, int* __restrict__ fillptr,
                          float* __restrict__ dinv, const int* __restrict__ counts,
                          const int* __restrict__ bsum, int N, int E) {
    int i = blockIdx.x * 256 + threadIdx.x;
    if (i < N) {
        int off = offsets[i] + bsum[i >> 10];
        offsets[i] = off;
        fillptr[i] = off;
        dinv[i] = rsqrtf((float)(counts[i] + 1));   // +1 self-loop
    }
    if (i == 0) offsets[N] = E;
}

// h2[n][c] = dinv[n] * sum_k x[n][k] * conv_w[c][k]
__global__ __launch_bounds__(256) void k_gemm1(const float* __restrict__ x,
                                               const float* __restrict__ cw,
                                               const float* __restrict__ dinv,
                                               float* __restrict__ h2, int N) {
    __shared__ float xt[64][64];
    int t = threadIdx.x;
    int lane = t & 63;
    int wv = t >> 6;
    int n0 = blockIdx.x * 64;

    float4 w[16];
    const float4* cw4 = (const float4*)(cw + lane * 64);
    #pragma unroll
    for (int i = 0; i < 16; i++) w[i] = cw4[i];

    const float4* x4 = (const float4*)x;
    float4* xt4 = (float4*)(&xt[0][0]);
    #pragma unroll
    for (int i = 0; i < 4; i++) {
        int idx = t + i * 256;            // 1024 float4 total
        int row = idx >> 4;
        int node = n0 + row;
        xt4[idx] = (node < N) ? x4[(size_t)node * 16 + (idx & 15)]
                              : make_float4(0.f, 0.f, 0.f, 0.f);
    }
    __syncthreads();

    for (int nl = wv * 16; nl < wv * 16 + 16; ++nl) {
        int node = n0 + nl;
        if (node >= N) break;
        const float4* xr = (const float4*)(&xt[nl][0]);
        float a = 0.f;
        #pragma unroll
        for (int i = 0; i < 16; i++) {
            float4 xv = xr[i];
            a += w[i].x * xv.x; a += w[i].y * xv.y;
            a += w[i].z * xv.z; a += w[i].w * xv.w;
        }
        h2[(size_t)node * 64 + lane] = a * dinv[node];
    }
}

__global__ void k_fill(const int* __restrict__ src, const int* __restrict__ dst, int E,
                       int* __restrict__ fillptr, int* __restrict__ csr) {
    int i = blockIdx.x * 256 + threadIdx.x;
    if (i < E) {
        int d = dst[i];
        int pos = atomicAdd(&fillptr[d], 1);
        csr[pos] = src[i];
    }
}

// hres[d][c] = relu(dinv[d]*(sum_{s in N(d)} h2[s][c] + h2[d][c]) + cb[c]) + x[d][c]
__global__ __launch_bounds__(256) void k_agg(const float* __restrict__ h2,
                                             const int* __restrict__ csr,
                                             const int* __restrict__ offsets,
                                             const float* __restrict__ dinv,
                                             const float* __restrict__ cb,
                                             const float* __restrict__ x,
                                             float* __restrict__ hres, int N) {
    int t = threadIdx.x;
    int lane = t & 63;
    int wv = t >> 6;
    int d = blockIdx.x * 4 + wv;
    if (d >= N) return;
    int r0 = offsets[d], r1 = offsets[d + 1];
    float val = h2[(size_t)d * 64 + lane];     // self-loop term
    int j = r0;
    for (; j + 1 < r1; j += 2) {
        int s0 = csr[j], s1 = csr[j + 1];
        float a = h2[(size_t)s0 * 64 + lane];
        float b = h2[(size_t)s1 * 64 + lane];
        val += a; val += b;
    }
    if (j < r1) val += h2[(size_t)csr[j] * 64 + lane];
    val *= dinv[d];
    val = fmaxf(val + cb[lane], 0.f) + x[(size_t)d * 64 + lane];
    hres[(size_t)d * 64 + lane] = val;
}

// Fused MLP: per-block tile of 32 nodes.
// phase2: h1[n][c] = relu(hres[n]·w1[c] + b1[c])  (thread = out channel c)
// phase3: h2[n][j] accumulated over k-chunks of 32 (w2 chunk staged in LDS);
//         thread = (node n = t&31, j-group jq = t>>5 owning 32 j's)
// phase4: out[n] = sum_j relu(h2)*w3[j] + b3 (8-way cross-thread reduce)
__global__ __launch_bounds__(256) void k_mlp(const float* __restrict__ hres,
                                             const float* __restrict__ w1,
                                             const float* __restrict__ b1,
                                             const float* __restrict__ w2,
                                             const float* __restrict__ b2,
                                             const float* __restrict__ w3,
                                             const float* __restrict__ b3,
                                             float* __restrict__ out, int N) {
    __shared__ float h1t[32][260];     // +4 pad: breaks bank conflicts on chunk loads
    __shared__ float region[8192];     // 32KB: hres tile overlay, then w2 chunks
    __shared__ float red[8][32];
    int t = threadIdx.x;
    int n0 = blockIdx.x * 32;

    // stage hres tile (32x64 = 512 float4)
    {
        const float4* hr4 = (const float4*)hres;
        float4* r4 = (float4*)region;
        #pragma unroll
        for (int i = 0; i < 2; i++) {
            int idx = t + i * 256;
            int row = idx >> 4;
            int node = n0 + row;
            r4[idx] = (node < N) ? hr4[(size_t)node * 16 + (idx & 15)]
                                 : make_float4(0.f, 0.f, 0.f, 0.f);
        }
    }
    float4 w1r[16];
    {
        const float4* p = (const float4*)(w1 + t * 64);
        #pragma unroll
        for (int i = 0; i < 16; i++) w1r[i] = p[i];
    }
    float b1v = b1[t];
    __syncthreads();

    // phase 2
    for (int n = 0; n < 32; n++) {
        const float4* xr = (const float4*)(region + n * 64);
        float a = 0.f;
        #pragma unroll
        for (int i = 0; i < 16; i++) {
            float4 xv = xr[i];
            a += w1r[i].x * xv.x; a += w1r[i].y * xv.y;
            a += w1r[i].z * xv.z; a += w1r[i].w * xv.w;
        }
        h1t[n][t] = fmaxf(a + b1v, 0.f);
    }

    // phase 3
    int n = t & 31, jq = t >> 5;
    float acc[32];
    #pragma unroll
    for (int jj = 0; jj < 32; jj++) acc[jj] = b2[jq * 32 + jj];

    for (int kc = 0; kc < 8; kc++) {
        __syncthreads();   // previous region readers done
        {
            const float4* w24 = (const float4*)w2;   // row stride = 64 float4
            float4* r4 = (float4*)region;
            #pragma unroll
            for (int i = 0; i < 8; i++) {
                int idx = t + i * 256;               // 2048 float4
                int j = idx >> 3, k4 = idx & 7;
                r4[idx] = w24[j * 64 + kc * 8 + k4];
            }
        }
        __syncthreads();
        float4 h1r[8];
        {
            const float4* hp = (const float4*)(&h1t[n][kc * 32]);
            #pragma unroll
            for (int q = 0; q < 8; q++) h1r[q] = hp[q];
        }
        #pragma unroll
        for (int jj = 0; jj < 32; jj++) {
            const float4* wr = (const float4*)(region + (jq * 32 + jj) * 32);
            float a = acc[jj];
            #pragma unroll
            for (int q = 0; q < 8; q++) {
                float4 wv = wr[q];
                a += wv.x * h1r[q].x; a += wv.y * h1r[q].y;
                a += wv.z * h1r[q].z; a += wv.w * h1r[q].w;
            }
            acc[jj] = a;
        }
    }

    // phase 4
    float partial = 0.f;
    #pragma unroll
    for (int jj = 0; jj < 32; jj++) partial += fmaxf(acc[jj], 0.f) * w3[jq * 32 + jj];
    red[jq][n] = partial;
    __syncthreads();
    if (t < 32) {
        float s = b3[0];
        #pragma unroll
        for (int q = 0; q < 8; q++) s += red[q][t];
        int node = n0 + t;
        if (node < N) out[node] = s;
    }
}

extern "C" void kernel_launch(void* const* d_in, const int* in_sizes, int n_in,
                              void* d_out, int out_size, void* d_ws, size_t ws_size,
                              hipStream_t stream) {
    const float* x  = (const float*)d_in[0];
    const int*   ei = (const int*)d_in[1];
    const float* cw = (const float*)d_in[2];
    const float* cb = (const float*)d_in[3];
    const float* w1 = (const float*)d_in[4];
    const float* b1 = (const float*)d_in[5];
    const float* w2 = (const float*)d_in[6];
    const float* b2 = (const float*)d_in[7];
    const float* w3 = (const float*)d_in[8];
    const float* b3 = (const float*)d_in[9];
    float* out = (float*)d_out;

    int N = in_sizes[0] / 64;
    int E = in_sizes[1] / 2;
    const int* src = ei;
    const int* dst = ei + E;

    char* ws = (char*)d_ws;
    size_t off = 0;
    auto alloc = [&](size_t bytes) {
        off = (off + 255) & ~(size_t)255;
        char* p = ws + off;
        off += bytes;
        return p;
    };
    int nb1 = (N + 1023) / 1024;
    int*   counts  = (int*)alloc((size_t)N * 4);
    int*   bsum    = (int*)alloc((size_t)nb1 * 4);
    int*   offsets = (int*)alloc(((size_t)N + 1) * 4);
    int*   fillptr = (int*)alloc((size_t)N * 4);
    float* dinv    = (float*)alloc((size_t)N * 4);
    float* h2      = (float*)alloc((size_t)N * 64 * 4);
    int*   csr     = (int*)alloc((size_t)E * 4);
    float* hres    = (float*)alloc((size_t)N * 64 * 4);
    (void)ws_size; (void)n_in; (void)out_size;

    hipMemsetAsync(counts, 0, (size_t)N * 4, stream);
    int nbE = (E + 255) / 256;
    k_count<<<nbE, 256, 0, stream>>>(dst, E, counts);
    k_scan1<<<nb1, 1024, 0, stream>>>(counts, N, offsets, bsum);
    k_scantop<<<1, 64, 0, stream>>>(bsum, nb1);
    k_scanadd<<<(N + 255) / 256, 256, 0, stream>>>(offsets, fillptr, dinv, counts, bsum, N, E);
    k_gemm1<<<(N + 63) / 64, 256, 0, stream>>>(x, cw, dinv, h2, N);
    k_fill<<<nbE, 256, 0, stream>>>(src, dst, E, fillptr, csr);
    k_agg<<<(N + 3) / 4, 256, 0, stream>>>(h2, csr, offsets, dinv, cb, x, hres, N);
    k_mlp<<<(N + 31) / 32, 256, 0, stream>>>(hres, w1, b1, w2, b2, w3, b3, out, N);
}

// Round 2
// 397.145 us; speedup vs baseline: 3.5516x; 3.5516x over previous
//
#include <hip/hip_runtime.h>

// ---------------------------------------------------------------------------
// GNN forward: GCNConv(64->64, sym-norm, self-loops) + ReLU + residual,
// then MLP 64->256->256->1 with ReLU.
// R1: MLP rewritten as fused bf16-MFMA GEMM (16x16x32), h1 stays in LDS,
// weights pre-converted to bf16 (L2-resident, loaded as fragments directly).
// hres stored bf16. CSR build / gemm1 / agg unchanged from R0.
// ---------------------------------------------------------------------------

typedef __bf16 bf16x8 __attribute__((ext_vector_type(8)));
typedef float f32x4 __attribute__((ext_vector_type(4)));
typedef unsigned int u32x4 __attribute__((ext_vector_type(4)));
typedef unsigned short u16x4 __attribute__((ext_vector_type(4)));

__device__ inline unsigned short f2b(float f) {
    unsigned int u = __builtin_bit_cast(unsigned int, f);
    u += 0x7fff + ((u >> 16) & 1);          // round-to-nearest-even
    return (unsigned short)(u >> 16);
}

__device__ inline bf16x8 ld_frag16(const void* p) {      // 16B-aligned
    u32x4 v = *(const u32x4*)p;
    return __builtin_bit_cast(bf16x8, v);
}

__global__ void k_count(const int* __restrict__ dst, int E, int* __restrict__ counts) {
    int i = blockIdx.x * 256 + threadIdx.x;
    if (i < E) atomicAdd(&counts[dst[i]], 1);
}

__global__ __launch_bounds__(1024) void k_scan1(const int* __restrict__ counts, int N,
                                                int* __restrict__ offsets, int* __restrict__ bsum) {
    __shared__ int s[1024];
    int t = threadIdx.x;
    int i = blockIdx.x * 1024 + t;
    int v = (i < N) ? counts[i] : 0;
    s[t] = v;
    __syncthreads();
    for (int off = 1; off < 1024; off <<= 1) {
        int a = (t >= off) ? s[t - off] : 0;
        __syncthreads();
        s[t] += a;
        __syncthreads();
    }
    if (i < N) offsets[i] = s[t] - v;
    if (t == 1023) bsum[blockIdx.x] = s[t];
}

__global__ void k_scantop(int* bsum, int nb) {
    if (threadIdx.x == 0 && blockIdx.x == 0) {
        int acc = 0;
        for (int b = 0; b < nb; b++) { int v = bsum[b]; bsum[b] = acc; acc += v; }
    }
}

__global__ void k_scanadd(int* __restrict__ offsets, int* __restrict__ fillptr,
                          float* __restrict__ dinv, const int* __restrict__ counts,
                          const int* __restrict__ bsum, int N, int E) {
    int i = blockIdx.x * 256 + threadIdx.x;
    if (i < N) {
        int off = offsets[i] + bsum[i >> 10];
        offsets[i] = off;
        fillptr[i] = off;
        dinv[i] = rsqrtf((float)(counts[i] + 1));
    }
    if (i == 0) offsets[N] = E;
}

// convert w1 (16384) and w2 (65536) to bf16
__global__ void k_cvt(const float* __restrict__ w1, const float* __restrict__ w2,
                      unsigned short* __restrict__ w1b, unsigned short* __restrict__ w2b) {
    int i = blockIdx.x * 256 + threadIdx.x;
    if (i < 16384) w1b[i] = f2b(w1[i]);
    if (i < 65536) w2b[i] = f2b(w2[i]);
}

// h2[n][c] = dinv[n] * sum_k x[n][k] * conv_w[c][k]   (fp32)
__global__ __launch_bounds__(256) void k_gemm1(const float* __restrict__ x,
                                               const float* __restrict__ cw,
                                               const float* __restrict__ dinv,
                                               float* __restrict__ h2, int N) {
    __shared__ float xt[64][64];
    int t = threadIdx.x;
    int lane = t & 63;
    int wv = t >> 6;
    int n0 = blockIdx.x * 64;

    float4 w[16];
    const float4* cw4 = (const float4*)(cw + lane * 64);
    #pragma unroll
    for (int i = 0; i < 16; i++) w[i] = cw4[i];

    const float4* x4 = (const float4*)x;
    float4* xt4 = (float4*)(&xt[0][0]);
    #pragma unroll
    for (int i = 0; i < 4; i++) {
        int idx = t + i * 256;
        int row = idx >> 4;
        int node = n0 + row;
        xt4[idx] = (node < N) ? x4[(size_t)node * 16 + (idx & 15)]
                              : make_float4(0.f, 0.f, 0.f, 0.f);
    }
    __syncthreads();

    for (int nl = wv * 16; nl < wv * 16 + 16; ++nl) {
        int node = n0 + nl;
        if (node >= N) break;
        const float4* xr = (const float4*)(&xt[nl][0]);
        float a = 0.f;
        #pragma unroll
        for (int i = 0; i < 16; i++) {
            float4 xv = xr[i];
            a += w[i].x * xv.x; a += w[i].y * xv.y;
            a += w[i].z * xv.z; a += w[i].w * xv.w;
        }
        h2[(size_t)node * 64 + lane] = a * dinv[node];
    }
}

__global__ void k_fill(const int* __restrict__ src, const int* __restrict__ dst, int E,
                       int* __restrict__ fillptr, int* __restrict__ csr) {
    int i = blockIdx.x * 256 + threadIdx.x;
    if (i < E) {
        int d = dst[i];
        int pos = atomicAdd(&fillptr[d], 1);
        csr[pos] = src[i];
    }
}

// hres[d][c] = bf16( relu(dinv[d]*(sum h2[s]+h2[d]) + cb[c]) + x[d][c] )
__global__ __launch_bounds__(256) void k_agg(const float* __restrict__ h2,
                                             const int* __restrict__ csr,
                                             const int* __restrict__ offsets,
                                             const float* __restrict__ dinv,
                                             const float* __restrict__ cb,
                                             const float* __restrict__ x,
                                             unsigned short* __restrict__ hres, int N) {
    int t = threadIdx.x;
    int lane = t & 63;
    int wv = t >> 6;
    int d = blockIdx.x * 4 + wv;
    if (d >= N) return;
    int r0 = offsets[d], r1 = offsets[d + 1];
    float val = h2[(size_t)d * 64 + lane];
    int j = r0;
    for (; j + 1 < r1; j += 2) {
        int s0 = csr[j], s1 = csr[j + 1];
        float a = h2[(size_t)s0 * 64 + lane];
        float b = h2[(size_t)s1 * 64 + lane];
        val += a; val += b;
    }
    if (j < r1) val += h2[(size_t)csr[j] * 64 + lane];
    val *= dinv[d];
    val = fmaxf(val + cb[lane], 0.f) + x[(size_t)d * 64 + lane];
    hres[(size_t)d * 64 + lane] = f2b(val);
}

// ---------------------------------------------------------------------------
// Fused MFMA MLP. Block = 128 nodes, 512 threads = 8 waves as 2(M) x 4(N).
// L1: C1(128x256) = H(128x64) @ W1^T, relu -> h1 LDS (bf16, swizzled)
// L2: C2(128x256) = h1 @ W2^T, relu
// L3: out = C2 @ w3 + b3 (VALU dot + shfl reduce)
// A-frag: lane l: row = base + (l&15), k = kk*32 + (l>>4)*8 .. +8
// B-frag: lane l: col = base + (l&15), same k  -> contiguous in W rows.
// LDS: h1 64KB + htile 16KB (overlaid by red[4][128] in L3) = 80KB -> 2 blk/CU
// ---------------------------------------------------------------------------
__global__ __launch_bounds__(512, 4) void k_mlp(const unsigned short* __restrict__ hres,
                                                const unsigned short* __restrict__ w1b,
                                                const float* __restrict__ b1,
                                                const unsigned short* __restrict__ w2b,
                                                const float* __restrict__ b2,
                                                const float* __restrict__ w3,
                                                const float* __restrict__ b3,
                                                float* __restrict__ out, int N) {
    __shared__ unsigned short h1t[32768];   // 128 x 256 bf16, row stride 512B, swizzled
    __shared__ unsigned short ht[8192];     // 128 x 64 bf16, row stride 128B, swizzled
    char* h1b = (char*)h1t;
    char* htb = (char*)ht;

    int t = threadIdx.x;
    int lane = t & 63;
    int wid = t >> 6;
    int wm = wid >> 2;           // 0..1  (row block of 64)
    int wn = wid & 3;            // 0..3  (col block of 64)
    int lr = lane & 15;          // fragment row/col index
    int lk = (lane >> 4) * 8;    // fragment k base
    int lg = lane >> 4;          // 0..3
    int n0 = blockIdx.x * 128;

    // ---- stage hres tile (bf16) into swizzled LDS ----
    {
        const u16x4* hr4 = (const u16x4*)hres;
        #pragma unroll
        for (int i = 0; i < 4; i++) {
            int idx = t + i * 512;          // 2048 = 128 rows * 16 u16x4
            int row = idx >> 4;
            int c4 = idx & 15;
            int node = n0 + row;
            u16x4 v = {0, 0, 0, 0};
            if (node < N) v = hr4[(size_t)node * 16 + c4];
            int byte = (row << 7) + (c4 << 3);
            byte ^= (row & 7) << 4;
            *(u16x4*)(htb + byte) = v;
        }
    }
    __syncthreads();

    // ---- layer 1: K=64 (2 k-steps) ----
    float bias1[4];
    #pragma unroll
    for (int nf = 0; nf < 4; nf++) bias1[nf] = b1[wn * 64 + nf * 16 + lr];

    f32x4 acc[4][4];
    #pragma unroll
    for (int mf = 0; mf < 4; mf++)
        #pragma unroll
        for (int nf = 0; nf < 4; nf++) {
            acc[mf][nf][0] = bias1[nf]; acc[mf][nf][1] = bias1[nf];
            acc[mf][nf][2] = bias1[nf]; acc[mf][nf][3] = bias1[nf];
        }

    #pragma unroll
    for (int kk = 0; kk < 2; kk++) {
        bf16x8 af[4], bfg[4];
        #pragma unroll
        for (int mf = 0; mf < 4; mf++) {
            int row = wm * 64 + mf * 16 + lr;
            int byte = (row << 7) + ((kk * 32 + lk) << 1);
            byte ^= (row & 7) << 4;
            af[mf] = ld_frag16(htb + byte);
        }
        #pragma unroll
        for (int nf = 0; nf < 4; nf++) {
            int c = wn * 64 + nf * 16 + lr;
            bfg[nf] = ld_frag16(w1b + c * 64 + kk * 32 + lk);
        }
        #pragma unroll
        for (int mf = 0; mf < 4; mf++)
            #pragma unroll
            for (int nf = 0; nf < 4; nf++)
                acc[mf][nf] = __builtin_amdgcn_mfma_f32_16x16x32_bf16(af[mf], bfg[nf], acc[mf][nf], 0, 0, 0);
    }

    // ---- relu + store h1 (bf16, swizzled) ----
    #pragma unroll
    for (int mf = 0; mf < 4; mf++)
        #pragma unroll
        for (int nf = 0; nf < 4; nf++)
            #pragma unroll
            for (int r = 0; r < 4; r++) {
                int row = wm * 64 + mf * 16 + lg * 4 + r;
                int col = wn * 64 + nf * 16 + lr;
                float v = fmaxf(acc[mf][nf][r], 0.f);
                int byte = (row << 9) + (col << 1);
                byte ^= (row & 7) << 4;
                *(unsigned short*)(h1b + byte) = f2b(v);
            }
    __syncthreads();

    // ---- layer 2: K=256 (8 k-steps) ----
    float bias2[4];
    #pragma unroll
    for (int nf = 0; nf < 4; nf++) bias2[nf] = b2[wn * 64 + nf * 16 + lr];
    #pragma unroll
    for (int mf = 0; mf < 4; mf++)
        #pragma unroll
        for (int nf = 0; nf < 4; nf++) {
            acc[mf][nf][0] = bias2[nf]; acc[mf][nf][1] = bias2[nf];
            acc[mf][nf][2] = bias2[nf]; acc[mf][nf][3] = bias2[nf];
        }

    #pragma unroll
    for (int kk = 0; kk < 8; kk++) {
        bf16x8 af[4], bfg[4];
        #pragma unroll
        for (int nf = 0; nf < 4; nf++) {
            int j = wn * 64 + nf * 16 + lr;
            bfg[nf] = ld_frag16(w2b + j * 256 + kk * 32 + lk);
        }
        #pragma unroll
        for (int mf = 0; mf < 4; mf++) {
            int row = wm * 64 + mf * 16 + lr;
            int byte = (row << 9) + ((kk * 32 + lk) << 1);
            byte ^= (row & 7) << 4;
            af[mf] = ld_frag16(h1b + byte);
        }
        #pragma unroll
        for (int mf = 0; mf < 4; mf++)
            #pragma unroll
            for (int nf = 0; nf < 4; nf++)
                acc[mf][nf] = __builtin_amdgcn_mfma_f32_16x16x32_bf16(af[mf], bfg[nf], acc[mf][nf], 0, 0, 0);
    }

    // ---- layer 3: relu(C2) . w3, reduce over 256 cols ----
    float w3v[4];
    #pragma unroll
    for (int nf = 0; nf < 4; nf++) w3v[nf] = w3[wn * 64 + nf * 16 + lr];

    float* red = (float*)htb;    // overlay: 4 * 128 floats = 2KB (htile dead)
    __syncthreads();             // ensure all htile readers done (layer1 long past)

    #pragma unroll
    for (int mf = 0; mf < 4; mf++)
        #pragma unroll
        for (int r = 0; r < 4; r++) {
            float p = 0.f;
            #pragma unroll
            for (int nf = 0; nf < 4; nf++)
                p += fmaxf(acc[mf][nf][r], 0.f) * w3v[nf];
            p += __shfl_xor(p, 1);
            p += __shfl_xor(p, 2);
            p += __shfl_xor(p, 4);
            p += __shfl_xor(p, 8);
            if (lr == 0) {
                int row = wm * 64 + mf * 16 + lg * 4 + r;
                red[wn * 128 + row] = p;
            }
        }
    __syncthreads();

    if (t < 128) {
        int node = n0 + t;
        if (node < N) {
            float s = b3[0] + red[t] + red[128 + t] + red[256 + t] + red[384 + t];
            out[node] = s;
        }
    }
}

extern "C" void kernel_launch(void* const* d_in, const int* in_sizes, int n_in,
                              void* d_out, int out_size, void* d_ws, size_t ws_size,
                              hipStream_t stream) {
    const float* x  = (const float*)d_in[0];
    const int*   ei = (const int*)d_in[1];
    const float* cw = (const float*)d_in[2];
    const float* cb = (const float*)d_in[3];
    const float* w1 = (const float*)d_in[4];
    const float* b1 = (const float*)d_in[5];
    const float* w2 = (const float*)d_in[6];
    const float* b2 = (const float*)d_in[7];
    const float* w3 = (const float*)d_in[8];
    const float* b3 = (const float*)d_in[9];
    float* out = (float*)d_out;

    int N = in_sizes[0] / 64;
    int E = in_sizes[1] / 2;
    const int* src = ei;
    const int* dst = ei + E;

    char* ws = (char*)d_ws;
    size_t off = 0;
    auto alloc = [&](size_t bytes) {
        off = (off + 255) & ~(size_t)255;
        char* p = ws + off;
        off += bytes;
        return p;
    };
    int nb1 = (N + 1023) / 1024;
    int*            counts  = (int*)alloc((size_t)N * 4);
    int*            bsum    = (int*)alloc((size_t)nb1 * 4);
    int*            offsets = (int*)alloc(((size_t)N + 1) * 4);
    int*            fillptr = (int*)alloc((size_t)N * 4);
    float*          dinv    = (float*)alloc((size_t)N * 4);
    float*          h2      = (float*)alloc((size_t)N * 64 * 4);
    int*            csr     = (int*)alloc((size_t)E * 4);
    unsigned short* hresb   = (unsigned short*)alloc((size_t)N * 64 * 2);
    unsigned short* w1b     = (unsigned short*)alloc((size_t)16384 * 2);
    unsigned short* w2b     = (unsigned short*)alloc((size_t)65536 * 2);
    (void)ws_size; (void)n_in; (void)out_size;

    hipMemsetAsync(counts, 0, (size_t)N * 4, stream);
    int nbE = (E + 255) / 256;
    k_count<<<nbE, 256, 0, stream>>>(dst, E, counts);
    k_scan1<<<nb1, 1024, 0, stream>>>(counts, N, offsets, bsum);
    k_scantop<<<1, 64, 0, stream>>>(bsum, nb1);
    k_scanadd<<<(N + 255) / 256, 256, 0, stream>>>(offsets, fillptr, dinv, counts, bsum, N, E);
    k_cvt<<<256, 256, 0, stream>>>(w1, w2, w1b, w2b);
    k_gemm1<<<(N + 63) / 64, 256, 0, stream>>>(x, cw, dinv, h2, N);
    k_fill<<<nbE, 256, 0, stream>>>(src, dst, E, fillptr, csr);
    k_agg<<<(N + 3) / 4, 256, 0, stream>>>(h2, csr, offsets, dinv, cb, x, hresb, N);
    k_mlp<<<(N + 127) / 128, 512, 0, stream>>>(hresb, w1b, b1, w2b, b2, w3, b3, out, N);
}

// Round 3
// 346.711 us; speedup vs baseline: 4.0683x; 1.1455x over previous
//
#include <hip/hip_runtime.h>

// ---------------------------------------------------------------------------
// GNN forward: GCNConv(64->64, sym-norm, self-loops) + ReLU + residual,
// then MLP 64->256->256->1 with ReLU.
// R2: k_fill rewritten slice-owned (dst-range per XCD -> L2-resident csr
// writes); h2 stored bf16 (halves gather traffic); scantop fused into
// scanadd; k_agg unrolled x4.
// ---------------------------------------------------------------------------

typedef __bf16 bf16x8 __attribute__((ext_vector_type(8)));
typedef float f32x4 __attribute__((ext_vector_type(4)));
typedef unsigned int u32x4 __attribute__((ext_vector_type(4)));
typedef unsigned short u16x4 __attribute__((ext_vector_type(4)));

__device__ inline unsigned short f2b(float f) {
    unsigned int u = __builtin_bit_cast(unsigned int, f);
    u += 0x7fff + ((u >> 16) & 1);          // round-to-nearest-even
    return (unsigned short)(u >> 16);
}

__device__ inline float b2f(unsigned short u) {
    unsigned int x = ((unsigned int)u) << 16;
    return __builtin_bit_cast(float, x);
}

__device__ inline bf16x8 ld_frag16(const void* p) {      // 16B-aligned
    u32x4 v = *(const u32x4*)p;
    return __builtin_bit_cast(bf16x8, v);
}

__global__ void k_count(const int* __restrict__ dst, int E, int* __restrict__ counts) {
    int i = blockIdx.x * 256 + threadIdx.x;
    if (i < E) atomicAdd(&counts[dst[i]], 1);
}

__global__ __launch_bounds__(1024) void k_scan1(const int* __restrict__ counts, int N,
                                                int* __restrict__ offsets, int* __restrict__ bsum) {
    __shared__ int s[1024];
    int t = threadIdx.x;
    int i = blockIdx.x * 1024 + t;
    int v = (i < N) ? counts[i] : 0;
    s[t] = v;
    __syncthreads();
    for (int off = 1; off < 1024; off <<= 1) {
        int a = (t >= off) ? s[t - off] : 0;
        __syncthreads();
        s[t] += a;
        __syncthreads();
    }
    if (i < N) offsets[i] = s[t] - v;
    if (t == 1023) bsum[blockIdx.x] = s[t];
}

// fused: per-block LDS scan of bsum (nb <= 128) + apply + dinv
__global__ void k_scanadd(int* __restrict__ offsets, int* __restrict__ fillptr,
                          float* __restrict__ dinv, const int* __restrict__ counts,
                          const int* __restrict__ bsum, int N, int E, int nb) {
    __shared__ int sb[128];
    int t = threadIdx.x;
    if (t < 128) sb[t] = (t < nb) ? bsum[t] : 0;
    __syncthreads();
    for (int off = 1; off < 128; off <<= 1) {
        int a = 0;
        if (t < 128 && t >= off) a = sb[t - off];
        __syncthreads();
        if (t < 128) sb[t] += a;
        __syncthreads();
    }
    int i = blockIdx.x * 256 + t;
    if (i < N) {
        int b = i >> 10;
        int pre = b ? sb[b - 1] : 0;
        int off2 = offsets[i] + pre;
        offsets[i] = off2;
        fillptr[i] = off2;
        dinv[i] = rsqrtf((float)(counts[i] + 1));
    }
    if (i == 0) offsets[N] = E;
}

// convert w1 (16384) and w2 (65536) to bf16
__global__ void k_cvt(const float* __restrict__ w1, const float* __restrict__ w2,
                      unsigned short* __restrict__ w1b, unsigned short* __restrict__ w2b) {
    int i = blockIdx.x * 256 + threadIdx.x;
    if (i < 16384) w1b[i] = f2b(w1[i]);
    if (i < 65536) w2b[i] = f2b(w2[i]);
}

// h2[n][c] = bf16( dinv[n] * sum_k x[n][k] * conv_w[c][k] )
__global__ __launch_bounds__(256) void k_gemm1(const float* __restrict__ x,
                                               const float* __restrict__ cw,
                                               const float* __restrict__ dinv,
                                               unsigned short* __restrict__ h2, int N) {
    __shared__ float xt[64][64];
    int t = threadIdx.x;
    int lane = t & 63;
    int wv = t >> 6;
    int n0 = blockIdx.x * 64;

    float4 w[16];
    const float4* cw4 = (const float4*)(cw + lane * 64);
    #pragma unroll
    for (int i = 0; i < 16; i++) w[i] = cw4[i];

    const float4* x4 = (const float4*)x;
    float4* xt4 = (float4*)(&xt[0][0]);
    #pragma unroll
    for (int i = 0; i < 4; i++) {
        int idx = t + i * 256;
        int row = idx >> 4;
        int node = n0 + row;
        xt4[idx] = (node < N) ? x4[(size_t)node * 16 + (idx & 15)]
                              : make_float4(0.f, 0.f, 0.f, 0.f);
    }
    __syncthreads();

    for (int nl = wv * 16; nl < wv * 16 + 16; ++nl) {
        int node = n0 + nl;
        if (node >= N) break;
        const float4* xr = (const float4*)(&xt[nl][0]);
        float a = 0.f;
        #pragma unroll
        for (int i = 0; i < 16; i++) {
            float4 xv = xr[i];
            a += w[i].x * xv.x; a += w[i].y * xv.y;
            a += w[i].z * xv.z; a += w[i].w * xv.w;
        }
        h2[(size_t)node * 64 + lane] = f2b(a * dinv[node]);
    }
}

// slice-owned CSR fill: slice = bid & 7 (maps to XCD via round-robin);
// each slice's csr window (~600KB) stays L2-resident -> dense writeback.
#define NSLICE 8
#define EPB 2048          // edges per block
__global__ void k_fill(const int* __restrict__ src, const int* __restrict__ dst, int E,
                       int* __restrict__ fillptr, int* __restrict__ csr, int sliceSz) {
    int bid = blockIdx.x;
    int slice = bid & (NSLICE - 1);
    int chunk = bid >> 3;
    int base = chunk * EPB;
    #pragma unroll
    for (int it = 0; it < EPB / 256; it++) {
        int i = base + it * 256 + threadIdx.x;
        if (i < E) {
            int d = dst[i];
            if (d / sliceSz == slice) {
                int pos = atomicAdd(&fillptr[d], 1);
                csr[pos] = src[i];
            }
        }
    }
}

// hres[d][c] = bf16( relu(dinv[d]*(sum h2[s]+h2[d]) + cb[c]) + x[d][c] )
__global__ __launch_bounds__(256) void k_agg(const unsigned short* __restrict__ h2,
                                             const int* __restrict__ csr,
                                             const int* __restrict__ offsets,
                                             const float* __restrict__ dinv,
                                             const float* __restrict__ cb,
                                             const float* __restrict__ x,
                                             unsigned short* __restrict__ hres, int N) {
    int t = threadIdx.x;
    int lane = t & 63;
    int wv = t >> 6;
    int d = blockIdx.x * 4 + wv;
    if (d >= N) return;
    int r0 = offsets[d], r1 = offsets[d + 1];
    float v0 = b2f(h2[(size_t)d * 64 + lane]);   // self-loop
    float v1 = 0.f, v2 = 0.f, v3 = 0.f;
    int j = r0;
    for (; j + 3 < r1; j += 4) {
        int s0 = csr[j], s1 = csr[j + 1], s2 = csr[j + 2], s3 = csr[j + 3];
        v0 += b2f(h2[(size_t)s0 * 64 + lane]);
        v1 += b2f(h2[(size_t)s1 * 64 + lane]);
        v2 += b2f(h2[(size_t)s2 * 64 + lane]);
        v3 += b2f(h2[(size_t)s3 * 64 + lane]);
    }
    for (; j < r1; j++) v0 += b2f(h2[(size_t)csr[j] * 64 + lane]);
    float val = (v0 + v1) + (v2 + v3);
    val *= dinv[d];
    val = fmaxf(val + cb[lane], 0.f) + x[(size_t)d * 64 + lane];
    hres[(size_t)d * 64 + lane] = f2b(val);
}

// ---------------------------------------------------------------------------
// Fused MFMA MLP (unchanged from R1). Block = 128 nodes, 8 waves 2(M)x4(N).
// ---------------------------------------------------------------------------
__global__ __launch_bounds__(512, 4) void k_mlp(const unsigned short* __restrict__ hres,
                                                const unsigned short* __restrict__ w1b,
                                                const float* __restrict__ b1,
                                                const unsigned short* __restrict__ w2b,
                                                const float* __restrict__ b2,
                                                const float* __restrict__ w3,
                                                const float* __restrict__ b3,
                                                float* __restrict__ out, int N) {
    __shared__ unsigned short h1t[32768];   // 128 x 256 bf16, swizzled
    __shared__ unsigned short ht[8192];     // 128 x 64 bf16, swizzled
    char* h1b = (char*)h1t;
    char* htb = (char*)ht;

    int t = threadIdx.x;
    int lane = t & 63;
    int wid = t >> 6;
    int wm = wid >> 2;
    int wn = wid & 3;
    int lr = lane & 15;
    int lk = (lane >> 4) * 8;
    int lg = lane >> 4;
    int n0 = blockIdx.x * 128;

    {
        const u16x4* hr4 = (const u16x4*)hres;
        #pragma unroll
        for (int i = 0; i < 4; i++) {
            int idx = t + i * 512;
            int row = idx >> 4;
            int c4 = idx & 15;
            int node = n0 + row;
            u16x4 v = {0, 0, 0, 0};
            if (node < N) v = hr4[(size_t)node * 16 + c4];
            int byte = (row << 7) + (c4 << 3);
            byte ^= (row & 7) << 4;
            *(u16x4*)(htb + byte) = v;
        }
    }
    __syncthreads();

    float bias1[4];
    #pragma unroll
    for (int nf = 0; nf < 4; nf++) bias1[nf] = b1[wn * 64 + nf * 16 + lr];

    f32x4 acc[4][4];
    #pragma unroll
    for (int mf = 0; mf < 4; mf++)
        #pragma unroll
        for (int nf = 0; nf < 4; nf++) {
            acc[mf][nf][0] = bias1[nf]; acc[mf][nf][1] = bias1[nf];
            acc[mf][nf][2] = bias1[nf]; acc[mf][nf][3] = bias1[nf];
        }

    #pragma unroll
    for (int kk = 0; kk < 2; kk++) {
        bf16x8 af[4], bfg[4];
        #pragma unroll
        for (int mf = 0; mf < 4; mf++) {
            int row = wm * 64 + mf * 16 + lr;
            int byte = (row << 7) + ((kk * 32 + lk) << 1);
            byte ^= (row & 7) << 4;
            af[mf] = ld_frag16(htb + byte);
        }
        #pragma unroll
        for (int nf = 0; nf < 4; nf++) {
            int c = wn * 64 + nf * 16 + lr;
            bfg[nf] = ld_frag16(w1b + c * 64 + kk * 32 + lk);
        }
        #pragma unroll
        for (int mf = 0; mf < 4; mf++)
            #pragma unroll
            for (int nf = 0; nf < 4; nf++)
                acc[mf][nf] = __builtin_amdgcn_mfma_f32_16x16x32_bf16(af[mf], bfg[nf], acc[mf][nf], 0, 0, 0);
    }

    #pragma unroll
    for (int mf = 0; mf < 4; mf++)
        #pragma unroll
        for (int nf = 0; nf < 4; nf++)
            #pragma unroll
            for (int r = 0; r < 4; r++) {
                int row = wm * 64 + mf * 16 + lg * 4 + r;
                int col = wn * 64 + nf * 16 + lr;
                float v = fmaxf(acc[mf][nf][r], 0.f);
                int byte = (row << 9) + (col << 1);
                byte ^= (row & 7) << 4;
                *(unsigned short*)(h1b + byte) = f2b(v);
            }
    __syncthreads();

    float bias2[4];
    #pragma unroll
    for (int nf = 0; nf < 4; nf++) bias2[nf] = b2[wn * 64 + nf * 16 + lr];
    #pragma unroll
    for (int mf = 0; mf < 4; mf++)
        #pragma unroll
        for (int nf = 0; nf < 4; nf++) {
            acc[mf][nf][0] = bias2[nf]; acc[mf][nf][1] = bias2[nf];
            acc[mf][nf][2] = bias2[nf]; acc[mf][nf][3] = bias2[nf];
        }

    #pragma unroll
    for (int kk = 0; kk < 8; kk++) {
        bf16x8 af[4], bfg[4];
        #pragma unroll
        for (int nf = 0; nf < 4; nf++) {
            int j = wn * 64 + nf * 16 + lr;
            bfg[nf] = ld_frag16(w2b + j * 256 + kk * 32 + lk);
        }
        #pragma unroll
        for (int mf = 0; mf < 4; mf++) {
            int row = wm * 64 + mf * 16 + lr;
            int byte = (row << 9) + ((kk * 32 + lk) << 1);
            byte ^= (row & 7) << 4;
            af[mf] = ld_frag16(h1b + byte);
        }
        #pragma unroll
        for (int mf = 0; mf < 4; mf++)
            #pragma unroll
            for (int nf = 0; nf < 4; nf++)
                acc[mf][nf] = __builtin_amdgcn_mfma_f32_16x16x32_bf16(af[mf], bfg[nf], acc[mf][nf], 0, 0, 0);
    }

    float w3v[4];
    #pragma unroll
    for (int nf = 0; nf < 4; nf++) w3v[nf] = w3[wn * 64 + nf * 16 + lr];

    float* red = (float*)htb;
    __syncthreads();

    #pragma unroll
    for (int mf = 0; mf < 4; mf++)
        #pragma unroll
        for (int r = 0; r < 4; r++) {
            float p = 0.f;
            #pragma unroll
            for (int nf = 0; nf < 4; nf++)
                p += fmaxf(acc[mf][nf][r], 0.f) * w3v[nf];
            p += __shfl_xor(p, 1);
            p += __shfl_xor(p, 2);
            p += __shfl_xor(p, 4);
            p += __shfl_xor(p, 8);
            if (lr == 0) {
                int row = wm * 64 + mf * 16 + lg * 4 + r;
                red[wn * 128 + row] = p;
            }
        }
    __syncthreads();

    if (t < 128) {
        int node = n0 + t;
        if (node < N) {
            float s = b3[0] + red[t] + red[128 + t] + red[256 + t] + red[384 + t];
            out[node] = s;
        }
    }
}

extern "C" void kernel_launch(void* const* d_in, const int* in_sizes, int n_in,
                              void* d_out, int out_size, void* d_ws, size_t ws_size,
                              hipStream_t stream) {
    const float* x  = (const float*)d_in[0];
    const int*   ei = (const int*)d_in[1];
    const float* cw = (const float*)d_in[2];
    const float* cb = (const float*)d_in[3];
    const float* w1 = (const float*)d_in[4];
    const float* b1 = (const float*)d_in[5];
    const float* w2 = (const float*)d_in[6];
    const float* b2 = (const float*)d_in[7];
    const float* w3 = (const float*)d_in[8];
    const float* b3 = (const float*)d_in[9];
    float* out = (float*)d_out;

    int N = in_sizes[0] / 64;
    int E = in_sizes[1] / 2;
    const int* src = ei;
    const int* dst = ei + E;

    char* ws = (char*)d_ws;
    size_t off = 0;
    auto alloc = [&](size_t bytes) {
        off = (off + 255) & ~(size_t)255;
        char* p = ws + off;
        off += bytes;
        return p;
    };
    int nb1 = (N + 1023) / 1024;
    int*            counts  = (int*)alloc((size_t)N * 4);
    int*            bsum    = (int*)alloc((size_t)nb1 * 4);
    int*            offsets = (int*)alloc(((size_t)N + 1) * 4);
    int*            fillptr = (int*)alloc((size_t)N * 4);
    float*          dinv    = (float*)alloc((size_t)N * 4);
    unsigned short* h2      = (unsigned short*)alloc((size_t)N * 64 * 2);
    int*            csr     = (int*)alloc((size_t)E * 4);
    unsigned short* hresb   = (unsigned short*)alloc((size_t)N * 64 * 2);
    unsigned short* w1b     = (unsigned short*)alloc((size_t)16384 * 2);
    unsigned short* w2b     = (unsigned short*)alloc((size_t)65536 * 2);
    (void)ws_size; (void)n_in; (void)out_size;

    hipMemsetAsync(counts, 0, (size_t)N * 4, stream);
    int nbE = (E + 255) / 256;
    k_count<<<nbE, 256, 0, stream>>>(dst, E, counts);
    k_scan1<<<nb1, 1024, 0, stream>>>(counts, N, offsets, bsum);
    k_scanadd<<<(N + 255) / 256, 256, 0, stream>>>(offsets, fillptr, dinv, counts, bsum, N, E, nb1);
    k_cvt<<<256, 256, 0, stream>>>(w1, w2, w1b, w2b);
    k_gemm1<<<(N + 63) / 64, 256, 0, stream>>>(x, cw, dinv, h2, N);
    int sliceSz = (N + NSLICE - 1) / NSLICE;
    int chunks = (E + EPB - 1) / EPB;
    k_fill<<<chunks * NSLICE, 256, 0, stream>>>(src, dst, E, fillptr, csr, sliceSz);
    k_agg<<<(N + 3) / 4, 256, 0, stream>>>(h2, csr, offsets, dinv, cb, x, hresb, N);
    k_mlp<<<(N + 127) / 128, 512, 0, stream>>>(hresb, w1b, b1, w2b, b2, w3, b3, out, N);
}